// Round 1
// baseline (771.205 us; speedup 1.0000x reference)
//
#include <hip/hip_runtime.h>
#include <hip/hip_bf16.h>
#include <math.h>

#define H1C 8
#define D1C 8
#define NCLS 40

// ---------------------------------------------------------------------------
// GEMM1: h1 = x @ W1  (N x 512) @ (512 x 64), epilogue: el1/er1 per head
// 64x64 tile per block, 256 threads, 4x4 microtile.
// ---------------------------------------------------------------------------
__global__ __launch_bounds__(256) void gemm1_kernel(
    const float* __restrict__ x, const float* __restrict__ W1,
    const float* __restrict__ al1, const float* __restrict__ ar1,
    float* __restrict__ h1, float* __restrict__ el1, float* __restrict__ er1,
    int Nn)
{
    __shared__ float xs[64 * 36];   // 64 rows x 32 k (pad to 36)
    __shared__ float wsh[32 * 68];  // 32 k x 64 cols (pad to 68)
    const int t = threadIdx.x;
    const int tile = blockIdx.x * 64;
    const int tx = t & 15;          // col group: cols tx*4 .. tx*4+3
    const int ty = t >> 4;          // row group: rows ty*4 .. ty*4+3

    float acc[4][4];
#pragma unroll
    for (int i = 0; i < 4; i++)
#pragma unroll
        for (int j = 0; j < 4; j++) acc[i][j] = 0.f;

    for (int k0 = 0; k0 < 512; k0 += 32) {
        // load x tile: thread t loads row r = t/4, cols (t%4)*8 .. +7
        {
            int r = t >> 2;
            int kk = (t & 3) * 8;
            int row = tile + r;
            float4 a, b;
            if (row < Nn) {
                const float* src = &x[(size_t)row * 512 + k0 + kk];
                a = *(const float4*)(src);
                b = *(const float4*)(src + 4);
            } else {
                a = make_float4(0.f, 0.f, 0.f, 0.f);
                b = a;
            }
            *(float4*)&xs[r * 36 + kk] = a;
            *(float4*)&xs[r * 36 + kk + 4] = b;
        }
        // load W tile: thread t loads k row kk = t/8, cols (t%8)*8 .. +7
        {
            int kk = t >> 3;
            int c = (t & 7) * 8;
            const float* src = &W1[(size_t)(k0 + kk) * 64 + c];
            float4 a = *(const float4*)(src);
            float4 b = *(const float4*)(src + 4);
            *(float4*)&wsh[kk * 68 + c] = a;
            *(float4*)&wsh[kk * 68 + c + 4] = b;
        }
        __syncthreads();
#pragma unroll
        for (int kk = 0; kk < 32; kk += 4) {
            float4 xv[4], wv[4];
#pragma unroll
            for (int i = 0; i < 4; i++) xv[i] = *(const float4*)&xs[(ty * 4 + i) * 36 + kk];
#pragma unroll
            for (int j = 0; j < 4; j++) wv[j] = *(const float4*)&wsh[(kk + j) * 68 + tx * 4];
#pragma unroll
            for (int i = 0; i < 4; i++) {
                float4 xi = xv[i];
                acc[i][0] += xi.x * wv[0].x + xi.y * wv[1].x + xi.z * wv[2].x + xi.w * wv[3].x;
                acc[i][1] += xi.x * wv[0].y + xi.y * wv[1].y + xi.z * wv[2].y + xi.w * wv[3].y;
                acc[i][2] += xi.x * wv[0].z + xi.y * wv[1].z + xi.z * wv[2].z + xi.w * wv[3].z;
                acc[i][3] += xi.x * wv[0].w + xi.y * wv[1].w + xi.z * wv[2].w + xi.w * wv[3].w;
            }
        }
        __syncthreads();
    }

    // epilogue: store h1, compute el1/er1 (head = col/8; two threads per head)
    float a0 = al1[tx * 4 + 0], a1 = al1[tx * 4 + 1], a2 = al1[tx * 4 + 2], a3 = al1[tx * 4 + 3];
    float r0 = ar1[tx * 4 + 0], r1 = ar1[tx * 4 + 1], r2 = ar1[tx * 4 + 2], r3 = ar1[tx * 4 + 3];
#pragma unroll
    for (int i = 0; i < 4; i++) {
        int row = tile + ty * 4 + i;
        bool ok = row < Nn;
        float pel = acc[i][0] * a0 + acc[i][1] * a1 + acc[i][2] * a2 + acc[i][3] * a3;
        float per = acc[i][0] * r0 + acc[i][1] * r1 + acc[i][2] * r2 + acc[i][3] * r3;
        pel += __shfl_xor(pel, 1);
        per += __shfl_xor(per, 1);
        if (ok) {
            *(float4*)&h1[(size_t)row * 64 + tx * 4] =
                make_float4(acc[i][0], acc[i][1], acc[i][2], acc[i][3]);
            if ((tx & 1) == 0) {
                el1[row * 8 + (tx >> 1)] = pel;
                er1[row * 8 + (tx >> 1)] = per;
            }
        }
    }
}

// ---------------------------------------------------------------------------
// CSR build: count, 2-level scan, scatter
// ---------------------------------------------------------------------------
__global__ __launch_bounds__(256) void count_kernel(const int* __restrict__ dst,
                                                    int* __restrict__ counts, int Ee)
{
    int i = blockIdx.x * blockDim.x + threadIdx.x;
    if (i < Ee) atomicAdd(&counts[dst[i]], 1);
}

__global__ __launch_bounds__(256) void scan1_kernel(const int* __restrict__ counts,
                                                    int* __restrict__ row_start,
                                                    int* __restrict__ blockSums, int Nn)
{
    __shared__ int s[256];
    int tid = threadIdx.x;
    int i = blockIdx.x * 256 + tid;
    int v = (i < Nn) ? counts[i] : 0;
    s[tid] = v;
    __syncthreads();
#pragma unroll
    for (int o = 1; o < 256; o <<= 1) {
        int t = (tid >= o) ? s[tid - o] : 0;
        __syncthreads();
        s[tid] += t;
        __syncthreads();
    }
    if (i < Nn) row_start[i] = s[tid] - v;  // exclusive within block
    if (tid == 255) blockSums[blockIdx.x] = s[255];
}

__global__ __launch_bounds__(512) void scan2_kernel(int* __restrict__ blockSums, int nb)
{
    __shared__ int s[512];
    int tid = threadIdx.x;
    int v = (tid < nb) ? blockSums[tid] : 0;
    s[tid] = v;
    __syncthreads();
#pragma unroll
    for (int o = 1; o < 512; o <<= 1) {
        int t = (tid >= o) ? s[tid - o] : 0;
        __syncthreads();
        s[tid] += t;
        __syncthreads();
    }
    if (tid < nb) blockSums[tid] = s[tid] - v;  // exclusive
}

__global__ __launch_bounds__(256) void scan3_kernel(int* __restrict__ row_start,
                                                    const int* __restrict__ blockOffs,
                                                    int* __restrict__ row_cur, int Nn, int Ee)
{
    int i = blockIdx.x * blockDim.x + threadIdx.x;
    if (i < Nn) {
        int v = row_start[i] + blockOffs[i >> 8];
        row_start[i] = v;
        row_cur[i] = v;
    }
    if (i == 0) row_start[Nn] = Ee;
}

__global__ __launch_bounds__(256) void scatter_kernel(const int* __restrict__ src,
                                                      const int* __restrict__ dst,
                                                      int* __restrict__ row_cur,
                                                      int* __restrict__ perm_src, int Ee)
{
    int i = blockIdx.x * blockDim.x + threadIdx.x;
    if (i < Ee) {
        int p = atomicAdd(&row_cur[dst[i]], 1);
        perm_src[p] = src[i];
    }
}

// ---------------------------------------------------------------------------
// Layer-1 aggregation: one wavefront per dst node. lane = h*8+d.
// 2-pass segment softmax; epilogue adds b1 + ELU -> h_mid
// ---------------------------------------------------------------------------
__global__ __launch_bounds__(256) void agg1_kernel(
    const float* __restrict__ h1, const float* __restrict__ el1,
    const float* __restrict__ er1, const int* __restrict__ row_start,
    const int* __restrict__ perm_src, const float* __restrict__ b1,
    float* __restrict__ h_mid, int Nn)
{
    int wid = (blockIdx.x * blockDim.x + threadIdx.x) >> 6;
    int lane = threadIdx.x & 63;
    if (wid >= Nn) return;
    const int n = wid;
    const int h = lane >> 3, d = lane & 7;
    const int beg = row_start[n], end = row_start[n + 1];
    const float er = er1[n * 8 + h];

    // pass 1: per-head max (8 lanes of the head group split the edges)
    float m = -INFINITY;
    for (int i = beg + d; i < end; i += 8) {
        int s = perm_src[i];
        float e = el1[s * 8 + h] + er;
        e = (e >= 0.f) ? e : 0.2f * e;
        m = fmaxf(m, e);
    }
    m = fmaxf(m, __shfl_xor(m, 1));
    m = fmaxf(m, __shfl_xor(m, 2));
    m = fmaxf(m, __shfl_xor(m, 4));

    // pass 2: weighted accumulate
    float acc = 0.f, denom = 0.f;
    for (int i = beg; i < end; ++i) {
        int s = perm_src[i];
        float e = el1[s * 8 + h] + er;
        e = (e >= 0.f) ? e : 0.2f * e;
        float w = __expf(e - m);
        denom += w;
        acc += h1[(size_t)s * 64 + lane] * w;
    }
    float v = acc / (denom + 1e-9f) + b1[lane];
    v = (v > 0.f) ? v : expm1f(v);  // ELU
    h_mid[(size_t)n * 64 + lane] = v;
}

// ---------------------------------------------------------------------------
// prep2: wal2[k] = sum_c W2[k][c]*al2[c]; war2 likewise
// ---------------------------------------------------------------------------
__global__ __launch_bounds__(64) void prep2_kernel(const float* __restrict__ W2,
                                                   const float* __restrict__ al2,
                                                   const float* __restrict__ ar2,
                                                   float* __restrict__ wal2,
                                                   float* __restrict__ war2)
{
    int k = threadIdx.x;  // 64
    float a = 0.f, b = 0.f;
    for (int c = 0; c < NCLS; c++) {
        float w = W2[k * NCLS + c];
        a += w * al2[c];
        b += w * ar2[c];
    }
    wal2[k] = a;
    war2[k] = b;
}

// ---------------------------------------------------------------------------
// GEMM2: h2 = h_mid @ W2 (N x 64 @ 64 x 40) + el2/er2. One thread per node.
// ---------------------------------------------------------------------------
__global__ __launch_bounds__(256) void gemm2_kernel(
    const float* __restrict__ h_mid, const float* __restrict__ W2,
    const float* __restrict__ wal2, const float* __restrict__ war2,
    float* __restrict__ h2, float* __restrict__ el2, float* __restrict__ er2,
    int Nn)
{
    __shared__ float w2s[64 * NCLS];
    __shared__ float wals[64], wars[64];
    for (int i = threadIdx.x; i < 64 * NCLS; i += blockDim.x) w2s[i] = W2[i];
    if (threadIdx.x < 64) {
        wals[threadIdx.x] = wal2[threadIdx.x];
        wars[threadIdx.x] = war2[threadIdx.x];
    }
    __syncthreads();
    int n = blockIdx.x * blockDim.x + threadIdx.x;
    if (n >= Nn) return;

    float out[NCLS];
#pragma unroll
    for (int c = 0; c < NCLS; c++) out[c] = 0.f;
    float accel = 0.f, accer = 0.f;

#pragma unroll 4
    for (int k4 = 0; k4 < 16; k4++) {
        float4 hv = *(const float4*)&h_mid[(size_t)n * 64 + k4 * 4];
        accel += hv.x * wals[k4 * 4] + hv.y * wals[k4 * 4 + 1] + hv.z * wals[k4 * 4 + 2] + hv.w * wals[k4 * 4 + 3];
        accer += hv.x * wars[k4 * 4] + hv.y * wars[k4 * 4 + 1] + hv.z * wars[k4 * 4 + 2] + hv.w * wars[k4 * 4 + 3];
#pragma unroll
        for (int c = 0; c < NCLS; c++) {
            out[c] += hv.x * w2s[(k4 * 4 + 0) * NCLS + c] + hv.y * w2s[(k4 * 4 + 1) * NCLS + c] +
                      hv.z * w2s[(k4 * 4 + 2) * NCLS + c] + hv.w * w2s[(k4 * 4 + 3) * NCLS + c];
        }
    }
    el2[n] = accel;
    er2[n] = accer;
#pragma unroll
    for (int c = 0; c < NCLS; c++) h2[(size_t)n * NCLS + c] = out[c];
}

// ---------------------------------------------------------------------------
// Layer-2 aggregation + log_softmax. One wavefront per dst node; lane=class.
// ---------------------------------------------------------------------------
__global__ __launch_bounds__(256) void agg2_kernel(
    const float* __restrict__ h2, const float* __restrict__ el2,
    const float* __restrict__ er2, const int* __restrict__ row_start,
    const int* __restrict__ perm_src, const float* __restrict__ b2,
    float* __restrict__ out, int Nn)
{
    int wid = (blockIdx.x * blockDim.x + threadIdx.x) >> 6;
    int lane = threadIdx.x & 63;
    if (wid >= Nn) return;
    const int n = wid;
    const int beg = row_start[n], end = row_start[n + 1];
    const float er = er2[n];

    // pass 1: max over edges (all 64 lanes split edges)
    float m = -INFINITY;
    for (int i = beg + lane; i < end; i += 64) {
        float e = el2[perm_src[i]] + er;
        e = (e >= 0.f) ? e : 0.2f * e;
        m = fmaxf(m, e);
    }
#pragma unroll
    for (int o = 1; o < 64; o <<= 1) m = fmaxf(m, __shfl_xor(m, o));

    // pass 2
    const bool act = lane < NCLS;
    float acc = 0.f, denom = 0.f;
    for (int i = beg; i < end; ++i) {
        int s = perm_src[i];
        float e = el2[s] + er;
        e = (e >= 0.f) ? e : 0.2f * e;
        float w = __expf(e - m);
        denom += w;
        if (act) acc += h2[(size_t)s * NCLS + lane] * w;
    }
    float v = act ? (acc / (denom + 1e-9f) + b2[lane]) : -INFINITY;

    // log_softmax over 40 classes
    float mx = v;
#pragma unroll
    for (int o = 1; o < 64; o <<= 1) mx = fmaxf(mx, __shfl_xor(mx, o));
    float sx = act ? __expf(v - mx) : 0.f;
#pragma unroll
    for (int o = 1; o < 64; o <<= 1) sx += __shfl_xor(sx, o);
    if (act) out[(size_t)n * NCLS + lane] = v - mx - logf(sx);
}

// ---------------------------------------------------------------------------
extern "C" void kernel_launch(void* const* d_in, const int* in_sizes, int n_in,
                              void* d_out, int out_size, void* d_ws, size_t ws_size,
                              hipStream_t stream)
{
    const float* x   = (const float*)d_in[0];
    const int*   src = (const int*)d_in[1];
    const int*   dst = (const int*)d_in[2];
    const float* W1  = (const float*)d_in[3];
    const float* al1 = (const float*)d_in[4];
    const float* ar1 = (const float*)d_in[5];
    const float* b1  = (const float*)d_in[6];
    const float* W2  = (const float*)d_in[7];
    const float* al2 = (const float*)d_in[8];
    const float* ar2 = (const float*)d_in[9];
    const float* b2  = (const float*)d_in[10];
    float* out = (float*)d_out;

    const int Nn = in_sizes[0] / 512;
    const int Ee = in_sizes[1];

    // workspace layout
    float* ws = (float*)d_ws;
    float* h1    = ws;                  // N*64
    float* el1   = h1 + (size_t)Nn * 64;
    float* er1   = el1 + (size_t)Nn * 8;
    float* h_mid = er1 + (size_t)Nn * 8;   // N*64
    float* h2    = h_mid + (size_t)Nn * 64;  // N*40
    float* el2   = h2 + (size_t)Nn * NCLS;
    float* er2   = el2 + Nn;
    float* wal2  = er2 + Nn;            // 64
    float* war2  = wal2 + 64;           // 64
    int* counts    = (int*)(war2 + 64);   // N
    int* row_start = counts + Nn;         // N+1
    int* row_cur   = row_start + Nn + 1;  // N
    int* blockOffs = row_cur + Nn;        // 512
    int* perm_src  = blockOffs + 512;     // E

    const int nb = (Nn + 255) / 256;

    // CSR build
    hipMemsetAsync(counts, 0, (size_t)Nn * sizeof(int), stream);
    count_kernel<<<(Ee + 255) / 256, 256, 0, stream>>>(dst, counts, Ee);
    scan1_kernel<<<nb, 256, 0, stream>>>(counts, row_start, blockOffs, Nn);
    scan2_kernel<<<1, 512, 0, stream>>>(blockOffs, nb);
    scan3_kernel<<<nb, 256, 0, stream>>>(row_start, blockOffs, row_cur, Nn, Ee);
    scatter_kernel<<<(Ee + 255) / 256, 256, 0, stream>>>(src, dst, row_cur, perm_src, Ee);

    // layer 1
    gemm1_kernel<<<(Nn + 63) / 64, 256, 0, stream>>>(x, W1, al1, ar1, h1, el1, er1, Nn);
    agg1_kernel<<<(Nn + 3) / 4, 256, 0, stream>>>(h1, el1, er1, row_start, perm_src, b1, h_mid, Nn);

    // layer 2
    prep2_kernel<<<1, 64, 0, stream>>>(W2, al2, ar2, wal2, war2);
    gemm2_kernel<<<(Nn + 255) / 256, 256, 0, stream>>>(h_mid, W2, wal2, war2, h2, el2, er2, Nn);
    agg2_kernel<<<(Nn + 3) / 4, 256, 0, stream>>>(h2, el2, er2, row_start, perm_src, b2, out, Nn);
}

// Round 2
// 412.778 us; speedup vs baseline: 1.8683x; 1.8683x over previous
//
#include <hip/hip_runtime.h>
#include <hip/hip_bf16.h>
#include <math.h>

#define NCLS 40

typedef __attribute__((ext_vector_type(8))) short bf16x8;
typedef __attribute__((ext_vector_type(4))) float f32x4;

__device__ inline float bf2f(ushort u) {
    unsigned v = ((unsigned)u) << 16;
    float f;
    __builtin_memcpy(&f, &v, 4);
    return f;
}
__device__ inline ushort f2bf(float f) {
    unsigned v;
    __builtin_memcpy(&v, &f, 4);
    unsigned r = (v + 0x7FFFu + ((v >> 16) & 1u)) >> 16;
    return (ushort)r;
}

// ---------------------------------------------------------------------------
// convW1: W1 [512][64] fp32 -> W1t [64][512] bf16 (transposed)
// ---------------------------------------------------------------------------
__global__ __launch_bounds__(256) void convW1_kernel(const float* __restrict__ W1,
                                                     ushort* __restrict__ W1t)
{
    int id = blockIdx.x * 256 + threadIdx.x;  // 32768
    if (id >= 512 * 64) return;
    int k = id >> 6, c = id & 63;
    W1t[c * 512 + k] = f2bf(W1[k * 64 + c]);
}

// ---------------------------------------------------------------------------
// GEMM1 (MFMA): h1b = bf16(x) @ bf16(W1). 64-row tile, 256 thr = 4 waves.
// wave w computes rows w*16..w*16+15, all 64 cols (4 col-blocks of 16).
// ---------------------------------------------------------------------------
__global__ __launch_bounds__(256) void gemm1_mfma_kernel(
    const float* __restrict__ x, const ushort* __restrict__ W1t,
    ushort* __restrict__ h1b, int Nn)
{
    __shared__ ushort As[64 * 40];  // 64 rows x 32 k (pad stride 40)
    __shared__ ushort Bs[64 * 40];  // 64 cols x 32 k (pad stride 40)
    const int t = threadIdx.x;
    const int lane = t & 63, w = t >> 6;
    const int tile = blockIdx.x * 64;

    f32x4 acc[4] = {};  // one 16x16 frag per col-block

    const int sr = t >> 2;         // staging row/col 0..63
    const int sk = (t & 3) * 8;    // k offset 0,8,16,24
    const int arow = tile + sr;
    const bool rowok = arow < Nn;
    const float* xrow = x + (size_t)arow * 512;
    const ushort* wrow = W1t + (size_t)sr * 512;

    const int r = lane & 15, g = lane >> 4;

    for (int k0 = 0; k0 < 512; k0 += 32) {
        // stage A (convert fp32 -> bf16)
        float4 f0, f1;
        if (rowok) {
            f0 = *(const float4*)(xrow + k0 + sk);
            f1 = *(const float4*)(xrow + k0 + sk + 4);
        } else {
            f0 = make_float4(0.f, 0.f, 0.f, 0.f);
            f1 = f0;
        }
        ushort* ap = &As[sr * 40 + sk];
        ap[0] = f2bf(f0.x); ap[1] = f2bf(f0.y); ap[2] = f2bf(f0.z); ap[3] = f2bf(f0.w);
        ap[4] = f2bf(f1.x); ap[5] = f2bf(f1.y); ap[6] = f2bf(f1.z); ap[7] = f2bf(f1.w);
        // stage B (already bf16, coalesced 16B)
        *(bf16x8*)&Bs[sr * 40 + sk] = *(const bf16x8*)(wrow + k0 + sk);
        __syncthreads();

        bf16x8 afrag = *(const bf16x8*)&As[(w * 16 + r) * 40 + g * 8];
#pragma unroll
        for (int cb = 0; cb < 4; cb++) {
            bf16x8 bfrag = *(const bf16x8*)&Bs[(cb * 16 + r) * 40 + g * 8];
            acc[cb] = __builtin_amdgcn_mfma_f32_16x16x32_bf16(afrag, bfrag, acc[cb], 0, 0, 0);
        }
        __syncthreads();
    }

    // store: C layout col = lane&15, row = (lane>>4)*4 + v
#pragma unroll
    for (int cb = 0; cb < 4; cb++) {
#pragma unroll
        for (int v = 0; v < 4; v++) {
            int row = tile + w * 16 + g * 4 + v;
            if (row < Nn) h1b[(size_t)row * 64 + cb * 16 + r] = f2bf(acc[cb][v]);
        }
    }
}

// ---------------------------------------------------------------------------
// elr1: el1[n,h] = sum_d h1[n,h,d]*al1[h,d]; er1 likewise. thread = n*8+h.
// ---------------------------------------------------------------------------
__global__ __launch_bounds__(256) void elr1_kernel(
    const ushort* __restrict__ h1b, const float* __restrict__ al1,
    const float* __restrict__ ar1, float* __restrict__ el1,
    float* __restrict__ er1, int Nn)
{
    int id = blockIdx.x * 256 + threadIdx.x;
    if (id >= Nn * 8) return;
    int h = id & 7;
    const ushort* p = h1b + (size_t)id * 8;
    ushort4 u0 = *(const ushort4*)p;
    ushort4 u1 = *(const ushort4*)(p + 4);
    float v0 = bf2f(u0.x), v1 = bf2f(u0.y), v2 = bf2f(u0.z), v3 = bf2f(u0.w);
    float v4 = bf2f(u1.x), v5 = bf2f(u1.y), v6 = bf2f(u1.z), v7 = bf2f(u1.w);
    const float* a = al1 + h * 8;
    const float* b = ar1 + h * 8;
    el1[id] = v0 * a[0] + v1 * a[1] + v2 * a[2] + v3 * a[3] + v4 * a[4] + v5 * a[5] + v6 * a[6] + v7 * a[7];
    er1[id] = v0 * b[0] + v1 * b[1] + v2 * b[2] + v3 * b[3] + v4 * b[4] + v5 * b[5] + v6 * b[6] + v7 * b[7];
}

// ---------------------------------------------------------------------------
// CSR build: count, 2-level scan, scatter
// ---------------------------------------------------------------------------
__global__ __launch_bounds__(256) void count_kernel(const int* __restrict__ dst,
                                                    int* __restrict__ counts, int Ee)
{
    int i = blockIdx.x * blockDim.x + threadIdx.x;
    if (i < Ee) atomicAdd(&counts[dst[i]], 1);
}

__global__ __launch_bounds__(256) void scan1_kernel(const int* __restrict__ counts,
                                                    int* __restrict__ row_start,
                                                    int* __restrict__ blockSums, int Nn)
{
    __shared__ int s[256];
    int tid = threadIdx.x;
    int i = blockIdx.x * 256 + tid;
    int v = (i < Nn) ? counts[i] : 0;
    s[tid] = v;
    __syncthreads();
#pragma unroll
    for (int o = 1; o < 256; o <<= 1) {
        int t = (tid >= o) ? s[tid - o] : 0;
        __syncthreads();
        s[tid] += t;
        __syncthreads();
    }
    if (i < Nn) row_start[i] = s[tid] - v;
    if (tid == 255) blockSums[blockIdx.x] = s[255];
}

__global__ __launch_bounds__(512) void scan2_kernel(int* __restrict__ blockSums, int nb)
{
    __shared__ int s[512];
    int tid = threadIdx.x;
    int v = (tid < nb) ? blockSums[tid] : 0;
    s[tid] = v;
    __syncthreads();
#pragma unroll
    for (int o = 1; o < 512; o <<= 1) {
        int t = (tid >= o) ? s[tid - o] : 0;
        __syncthreads();
        s[tid] += t;
        __syncthreads();
    }
    if (tid < nb) blockSums[tid] = s[tid] - v;
}

__global__ __launch_bounds__(256) void scan3_kernel(int* __restrict__ row_start,
                                                    const int* __restrict__ blockOffs,
                                                    int* __restrict__ row_cur, int Nn, int Ee)
{
    int i = blockIdx.x * blockDim.x + threadIdx.x;
    if (i < Nn) {
        int v = row_start[i] + blockOffs[i >> 8];
        row_start[i] = v;
        row_cur[i] = v;
    }
    if (i == 0) row_start[Nn] = Ee;
}

__global__ __launch_bounds__(256) void scatter_kernel(const int* __restrict__ src,
                                                      const int* __restrict__ dst,
                                                      int* __restrict__ row_cur,
                                                      int* __restrict__ perm_src, int Ee)
{
    int i = blockIdx.x * blockDim.x + threadIdx.x;
    if (i < Ee) {
        int p = atomicAdd(&row_cur[dst[i]], 1);
        perm_src[p] = src[i];
    }
}

// ---------------------------------------------------------------------------
// agg1: one wave per dst node, lane = h*8+d. Single pass (no max; |e| small).
// perm indices batch-loaded coalesced + shfl broadcast; 4x unrolled gathers.
// ---------------------------------------------------------------------------
__global__ __launch_bounds__(256) void agg1_kernel(
    const ushort* __restrict__ h1b, const float* __restrict__ el1,
    const float* __restrict__ er1, const int* __restrict__ row_start,
    const int* __restrict__ perm_src, const float* __restrict__ b1,
    ushort* __restrict__ hmidb, int Nn)
{
    int wid = (blockIdx.x * blockDim.x + threadIdx.x) >> 6;
    int lane = threadIdx.x & 63;
    if (wid >= Nn) return;
    const int h = lane >> 3;
    const int beg = row_start[wid], end = row_start[wid + 1];
    const float er = er1[wid * 8 + h];

    float acc = 0.f, denom = 0.f;
    for (int i0 = beg; i0 < end; i0 += 64) {
        int cnt = min(end - i0, 64);
        int pv = (i0 + lane < end) ? perm_src[i0 + lane] : 0;
        int j = 0;
        for (; j + 4 <= cnt; j += 4) {
            int s0 = __shfl(pv, j), s1 = __shfl(pv, j + 1);
            int s2 = __shfl(pv, j + 2), s3 = __shfl(pv, j + 3);
            float e0 = el1[s0 * 8 + h] + er;
            float e1 = el1[s1 * 8 + h] + er;
            float e2 = el1[s2 * 8 + h] + er;
            float e3 = el1[s3 * 8 + h] + er;
            ushort r0 = h1b[(size_t)s0 * 64 + lane];
            ushort r1 = h1b[(size_t)s1 * 64 + lane];
            ushort r2 = h1b[(size_t)s2 * 64 + lane];
            ushort r3 = h1b[(size_t)s3 * 64 + lane];
            e0 = (e0 >= 0.f) ? e0 : 0.2f * e0;
            e1 = (e1 >= 0.f) ? e1 : 0.2f * e1;
            e2 = (e2 >= 0.f) ? e2 : 0.2f * e2;
            e3 = (e3 >= 0.f) ? e3 : 0.2f * e3;
            float w0 = __expf(fminf(e0, 80.f)), w1 = __expf(fminf(e1, 80.f));
            float w2 = __expf(fminf(e2, 80.f)), w3 = __expf(fminf(e3, 80.f));
            denom += (w0 + w1) + (w2 + w3);
            acc += bf2f(r0) * w0 + bf2f(r1) * w1 + bf2f(r2) * w2 + bf2f(r3) * w3;
        }
        for (; j < cnt; j++) {
            int s = __shfl(pv, j);
            float e = el1[s * 8 + h] + er;
            e = (e >= 0.f) ? e : 0.2f * e;
            float w = __expf(fminf(e, 80.f));
            denom += w;
            acc += bf2f(h1b[(size_t)s * 64 + lane]) * w;
        }
    }
    float v = acc / (denom + 1e-9f) + b1[lane];
    v = (v > 0.f) ? v : expm1f(v);  // ELU
    hmidb[(size_t)wid * 64 + lane] = f2bf(v);
}

// ---------------------------------------------------------------------------
// prep2: wal2[k] = sum_c W2[k][c]*al2[c]; war2 likewise
// ---------------------------------------------------------------------------
__global__ __launch_bounds__(64) void prep2_kernel(const float* __restrict__ W2,
                                                   const float* __restrict__ al2,
                                                   const float* __restrict__ ar2,
                                                   float* __restrict__ wal2,
                                                   float* __restrict__ war2)
{
    int k = threadIdx.x;  // 64
    float a = 0.f, b = 0.f;
    for (int c = 0; c < NCLS; c++) {
        float w = W2[k * NCLS + c];
        a += w * al2[c];
        b += w * ar2[c];
    }
    wal2[k] = a;
    war2[k] = b;
}

// ---------------------------------------------------------------------------
// GEMM2: h2b = hmid @ W2 (bf16 in, bf16 out) + el2/er2. One thread per node.
// ---------------------------------------------------------------------------
__global__ __launch_bounds__(256) void gemm2_kernel(
    const ushort* __restrict__ hmidb, const float* __restrict__ W2,
    const float* __restrict__ wal2, const float* __restrict__ war2,
    ushort* __restrict__ h2b, float* __restrict__ el2, float* __restrict__ er2,
    int Nn)
{
    __shared__ float w2s[64 * NCLS];
    __shared__ float wals[64], wars[64];
    for (int i = threadIdx.x; i < 64 * NCLS; i += blockDim.x) w2s[i] = W2[i];
    if (threadIdx.x < 64) {
        wals[threadIdx.x] = wal2[threadIdx.x];
        wars[threadIdx.x] = war2[threadIdx.x];
    }
    __syncthreads();
    int n = blockIdx.x * blockDim.x + threadIdx.x;
    if (n >= Nn) return;

    float out[NCLS];
#pragma unroll
    for (int c = 0; c < NCLS; c++) out[c] = 0.f;
    float accel = 0.f, accer = 0.f;

#pragma unroll 4
    for (int k4 = 0; k4 < 16; k4++) {
        ushort4 u = *(const ushort4*)&hmidb[(size_t)n * 64 + k4 * 4];
        float h0 = bf2f(u.x), h1 = bf2f(u.y), h2 = bf2f(u.z), h3 = bf2f(u.w);
        accel += h0 * wals[k4 * 4] + h1 * wals[k4 * 4 + 1] + h2 * wals[k4 * 4 + 2] + h3 * wals[k4 * 4 + 3];
        accer += h0 * wars[k4 * 4] + h1 * wars[k4 * 4 + 1] + h2 * wars[k4 * 4 + 2] + h3 * wars[k4 * 4 + 3];
#pragma unroll
        for (int c = 0; c < NCLS; c++) {
            out[c] += h0 * w2s[(k4 * 4 + 0) * NCLS + c] + h1 * w2s[(k4 * 4 + 1) * NCLS + c] +
                      h2 * w2s[(k4 * 4 + 2) * NCLS + c] + h3 * w2s[(k4 * 4 + 3) * NCLS + c];
        }
    }
    el2[n] = accel;
    er2[n] = accer;
#pragma unroll
    for (int c = 0; c < NCLS; c++) h2b[(size_t)n * NCLS + c] = f2bf(out[c]);
}

// ---------------------------------------------------------------------------
// agg2 + log_softmax: one wave per dst node; lane = class. Single pass.
// ---------------------------------------------------------------------------
__global__ __launch_bounds__(256) void agg2_kernel(
    const ushort* __restrict__ h2b, const float* __restrict__ el2,
    const float* __restrict__ er2, const int* __restrict__ row_start,
    const int* __restrict__ perm_src, const float* __restrict__ b2,
    float* __restrict__ out, int Nn)
{
    int wid = (blockIdx.x * blockDim.x + threadIdx.x) >> 6;
    int lane = threadIdx.x & 63;
    if (wid >= Nn) return;
    const int beg = row_start[wid], end = row_start[wid + 1];
    const float er = er2[wid];
    const bool act = lane < NCLS;
    const int cl = act ? lane : 0;

    float acc = 0.f, denom = 0.f;
    for (int i0 = beg; i0 < end; i0 += 64) {
        int cnt = min(end - i0, 64);
        int pv = (i0 + lane < end) ? perm_src[i0 + lane] : 0;
        int j = 0;
        for (; j + 4 <= cnt; j += 4) {
            int s0 = __shfl(pv, j), s1 = __shfl(pv, j + 1);
            int s2 = __shfl(pv, j + 2), s3 = __shfl(pv, j + 3);
            float e0 = el2[s0] + er, e1 = el2[s1] + er;
            float e2 = el2[s2] + er, e3 = el2[s3] + er;
            ushort r0 = h2b[(size_t)s0 * NCLS + cl];
            ushort r1 = h2b[(size_t)s1 * NCLS + cl];
            ushort r2 = h2b[(size_t)s2 * NCLS + cl];
            ushort r3 = h2b[(size_t)s3 * NCLS + cl];
            e0 = (e0 >= 0.f) ? e0 : 0.2f * e0;
            e1 = (e1 >= 0.f) ? e1 : 0.2f * e1;
            e2 = (e2 >= 0.f) ? e2 : 0.2f * e2;
            e3 = (e3 >= 0.f) ? e3 : 0.2f * e3;
            float w0 = __expf(fminf(e0, 80.f)), w1 = __expf(fminf(e1, 80.f));
            float w2 = __expf(fminf(e2, 80.f)), w3 = __expf(fminf(e3, 80.f));
            denom += (w0 + w1) + (w2 + w3);
            acc += bf2f(r0) * w0 + bf2f(r1) * w1 + bf2f(r2) * w2 + bf2f(r3) * w3;
        }
        for (; j < cnt; j++) {
            int s = __shfl(pv, j);
            float e = el2[s] + er;
            e = (e >= 0.f) ? e : 0.2f * e;
            float w = __expf(fminf(e, 80.f));
            denom += w;
            acc += bf2f(h2b[(size_t)s * NCLS + cl]) * w;
        }
    }
    float v = act ? (acc / (denom + 1e-9f) + b2[lane]) : -1e30f;

    // log_softmax over 40 classes
    float mx = v;
#pragma unroll
    for (int o = 1; o < 64; o <<= 1) mx = fmaxf(mx, __shfl_xor(mx, o));
    float sx = act ? __expf(v - mx) : 0.f;
#pragma unroll
    for (int o = 1; o < 64; o <<= 1) sx += __shfl_xor(sx, o);
    if (act) out[(size_t)wid * NCLS + lane] = v - mx - __logf(sx);
}

// ---------------------------------------------------------------------------
extern "C" void kernel_launch(void* const* d_in, const int* in_sizes, int n_in,
                              void* d_out, int out_size, void* d_ws, size_t ws_size,
                              hipStream_t stream)
{
    const float* x   = (const float*)d_in[0];
    const int*   src = (const int*)d_in[1];
    const int*   dst = (const int*)d_in[2];
    const float* W1  = (const float*)d_in[3];
    const float* al1 = (const float*)d_in[4];
    const float* ar1 = (const float*)d_in[5];
    const float* b1  = (const float*)d_in[6];
    const float* W2  = (const float*)d_in[7];
    const float* al2 = (const float*)d_in[8];
    const float* ar2 = (const float*)d_in[9];
    const float* b2  = (const float*)d_in[10];
    float* out = (float*)d_out;

    const int Nn = in_sizes[0] / 512;
    const int Ee = in_sizes[1];

    // workspace layout (bf16 feature buffers first, 16B-aligned blocks)
    ushort* h1b   = (ushort*)d_ws;                 // N*64
    ushort* hmidb = h1b + (size_t)Nn * 64;         // N*64
    ushort* h2b   = hmidb + (size_t)Nn * 64;       // N*40
    ushort* W1t   = h2b + (size_t)Nn * NCLS;       // 64*512
    float* el1  = (float*)(W1t + 64 * 512);        // N*8
    float* er1  = el1 + (size_t)Nn * 8;
    float* el2  = er1 + (size_t)Nn * 8;            // N
    float* er2  = el2 + Nn;
    float* wal2 = er2 + Nn;                        // 64
    float* war2 = wal2 + 64;                       // 64
    int* counts    = (int*)(war2 + 64);            // N
    int* row_start = counts + Nn;                  // N+1
    int* row_cur   = row_start + Nn + 1;           // N
    int* blockOffs = row_cur + Nn;                 // 512
    int* perm_src  = blockOffs + 512;              // E

    const int nb = (Nn + 255) / 256;

    // CSR build
    hipMemsetAsync(counts, 0, (size_t)Nn * sizeof(int), stream);
    count_kernel<<<(Ee + 255) / 256, 256, 0, stream>>>(dst, counts, Ee);
    scan1_kernel<<<nb, 256, 0, stream>>>(counts, row_start, blockOffs, Nn);
    scan2_kernel<<<1, 512, 0, stream>>>(blockOffs, nb);
    scan3_kernel<<<nb, 256, 0, stream>>>(row_start, blockOffs, row_cur, Nn, Ee);
    scatter_kernel<<<(Ee + 255) / 256, 256, 0, stream>>>(src, dst, row_cur, perm_src, Ee);

    // layer 1
    convW1_kernel<<<(512 * 64 + 255) / 256, 256, 0, stream>>>(W1, W1t);
    gemm1_mfma_kernel<<<(Nn + 63) / 64, 256, 0, stream>>>(x, W1t, h1b, Nn);
    elr1_kernel<<<(Nn * 8 + 255) / 256, 256, 0, stream>>>(h1b, al1, ar1, el1, er1, Nn);
    agg1_kernel<<<(Nn + 3) / 4, 256, 0, stream>>>(h1b, el1, er1, row_start, perm_src, b1, hmidb, Nn);

    // layer 2
    prep2_kernel<<<1, 64, 0, stream>>>(W2, al2, ar2, wal2, war2);
    gemm2_kernel<<<(Nn + 255) / 256, 256, 0, stream>>>(hmidb, W2, wal2, war2, h2b, el2, er2, Nn);
    agg2_kernel<<<(Nn + 3) / 4, 256, 0, stream>>>(h2b, el2, er2, row_start, perm_src, b2, out, Nn);
}